// Round 7
// baseline (82.137 us; speedup 1.0000x reference)
//
#include <hip/hip_runtime.h>
#include <hip/hip_bf16.h>
#include <math.h>

#define D_DIM   1024
#define NM      16
#define B_DIM   8
#define L_DIM   4096
#define SCALE_F 0.25f      // sqrt(1/N)
#define NK      5          // MFMA K-steps of 32 -> 160 taps total
#define WPB     4          // waves per block, one (b,d) row per wave
#define NTILE   16         // 4096 / 256 output tiles per row
#define WIN_E   4608       // LDS elements per wave: 256 zero-pad + 4096 row

typedef __attribute__((ext_vector_type(8))) short bf16x8;   // 8 bf16 (4 VGPRs)
typedef __attribute__((ext_vector_type(4))) float f32x4;

union U4 { uint4 u; bf16x8 v; };

__device__ __forceinline__ unsigned rot16(unsigned v) { return (v >> 16) | (v << 16); }
__device__ __forceinline__ unsigned short f2bf(float f) {
    __hip_bfloat16 h = __float2bfloat16(f);               // RNE
    return *reinterpret_cast<unsigned short*>(&h);
}
__device__ __forceinline__ float bflo(unsigned u) { return __uint_as_float(u << 16); }
__device__ __forceinline__ float bfhi(unsigned u) { return __uint_as_float(u & 0xffff0000u); }

// A-fragments for row-dimension d: A[i,t'] = k_d[i + t'], i = lane&15,
// t' = 32*k + 8*(lane>>4) + e - 15, e = 0..7 (zero for negative tap index).
__device__ void compute_afrag(int d, int lane,
                              const float* __restrict__ p_logit,
                              const float* __restrict__ lqr,
                              const float* __restrict__ lqi,
                              const float* __restrict__ gr,
                              const float* __restrict__ gi,
                              bf16x8 (&af)[NK])
{
    float LR[NM], LI[NM], CR[NM], CI[NM];
#pragma unroll
    for (int n = 0; n < NM; ++n) {
        const int idx = d * NM + n;
        const float p = 1.0f / (1.0f + __expf(-p_logit[idx]));
        LR[n] = lqr[idx]; LI[n] = lqi[idx];
        CR[n] = gr[idx] * (SCALE_F * p);
        CI[n] = gi[idx] * (SCALE_F * p);
    }
    const int i = lane & 15, g = lane >> 4;
#pragma unroll
    for (int k = 0; k < NK; ++k) {
        unsigned pk[4] = {0, 0, 0, 0};
#pragma unroll
        for (int e = 0; e < 8; ++e) {
            const int t = i - 15 + 32 * k + 8 * g + e;
            float v = 0.0f;
            if (t >= 0) {
                const float tf = (float)t;
#pragma unroll
                for (int n = 0; n < NM; ++n) {
                    const float er = __expf(tf * LR[n]);
                    float s, c; __sincosf(tf * LI[n], &s, &c);
                    v += er * fmaf(CR[n], c, -CI[n] * s);
                }
            }
            const unsigned b = f2bf(v);
            if ((e & 1) == 0) pk[e >> 1] = b; else pk[e >> 1] |= b << 16;
        }
        U4 u; u.u = make_uint4(pk[0], pk[1], pk[2], pk[3]); af[k] = u.v;
    }
}

// Kernel A: precompute A-fragments for all d into ws, exact per-lane order.
__global__ __launch_bounds__(64)
void ema_mkA(const float* __restrict__ p_logit, const float* __restrict__ lqr,
             const float* __restrict__ lqi, const float* __restrict__ gr,
             const float* __restrict__ gi, uint4* __restrict__ wsa)
{
    const int d = blockIdx.x, lane = threadIdx.x;
    bf16x8 af[NK];
    compute_afrag(d, lane, p_logit, lqr, lqi, gr, gi, af);
#pragma unroll
    for (int k = 0; k < NK; ++k) {
        U4 u; u.v = af[k];
        wsa[(size_t)(d * NK + k) * 64 + lane] = u.u;
    }
}

// Main kernel: one wave per (b,d) row. Stage the WHOLE row into LDS once
// (16 coalesced float4 loads, 2 batches of 8 for MLP), then all 16 output
// tiles run purely from LDS: 5x { ds_read_b128 + reverse + MFMA } + fused
// residual + dwordx4 store. R6's per-tile global staging exposed ~900cyc HBM
// latency 16x per wave (latency-bound: VALUBusy 15%, MfmaUtil 5%, HBM 31%).
template<bool FROM_WS>
__global__ __launch_bounds__(256)
void ema_fir(const float* __restrict__ x,
             const float* __restrict__ p_logit,
             const float* __restrict__ lqr, const float* __restrict__ lqi,
             const float* __restrict__ gr, const float* __restrict__ gi,
             const float* __restrict__ omega,
             const uint4* __restrict__ wsa,
             float* __restrict__ out)
{
    __shared__ __align__(16) unsigned short smem[WPB][WIN_E];  // 36 KB/block

    const int w    = threadIdx.x >> 6;
    const int lane = threadIdx.x & 63;
    const int row  = blockIdx.x * WPB + w;      // b*D + d
    const int d    = row & (D_DIM - 1);
    const int j    = lane & 15, g = lane >> 4;

    const float* xrow = x   + (size_t)row * L_DIM;
    float*       yrow = out + (size_t)row * L_DIM;
    const float  om   = omega[d];

    bf16x8 af[NK];
    if (FROM_WS) {
#pragma unroll
        for (int k = 0; k < NK; ++k) {
            U4 u; u.u = wsa[(size_t)(d * NK + k) * 64 + lane];
            af[k] = u.v;
        }
    } else {
        compute_afrag(d, lane, p_logit, lqr, lqi, gr, gi, af);
    }

    char* sbase = reinterpret_cast<char*>(&smem[w][0]);

    // ---- zero pad: elements [0,256) = bytes [0,512) ----
    *reinterpret_cast<uint2*>(sbase + lane * 8) = make_uint2(0u, 0u);

    // ---- stage full row as bf16: x[l] at byte 512 + 2l ----
#pragma unroll
    for (int half = 0; half < 2; ++half) {
        float4 b[8];
#pragma unroll
        for (int s = 0; s < 8; ++s)
            b[s] = *reinterpret_cast<const float4*>(xrow + (half * 8 + s) * 256 + lane * 4);
#pragma unroll
        for (int s = 0; s < 8; ++s) {
            uint2 pk;
            pk.x = (unsigned)f2bf(b[s].x) | ((unsigned)f2bf(b[s].y) << 16);
            pk.y = (unsigned)f2bf(b[s].z) | ((unsigned)f2bf(b[s].w) << 16);
            *reinterpret_cast<uint2*>(sbase + 512 + ((half * 8 + s) * 256 + lane * 4) * 2) = pk;
        }
    }
    // wave-private LDS, same-wave ds_write->ds_read: lgkmcnt ordering, no barrier.

    // ---- 16 tiles, all from LDS (R6 window math shifted by 512*t bytes) ----
#pragma unroll 1
    for (int t = 0; t < NTILE; ++t) {
        f32x4 acc = {0.0f, 0.0f, 0.0f, 0.0f};
#pragma unroll
        for (int k = 0; k < NK; ++k) {
            const int boff = 512 * t + 528 + 32 * j - 64 * k - 16 * g;  // 16B aligned
            U4 z; z.u = *reinterpret_cast<const uint4*>(sbase + boff);
            uint4 rv;
            rv.x = rot16(z.u.w); rv.y = rot16(z.u.z);
            rv.z = rot16(z.u.y); rv.w = rot16(z.u.x);
            U4 bfv; bfv.u = rv;
            acc = __builtin_amdgcn_mfma_f32_16x16x32_bf16(af[k], bfv.v, acc, 0, 0, 0);
        }
        const int lx = 512 * t + 512 + 32 * j + 8 * g;
        const uint2 z2 = *reinterpret_cast<const uint2*>(sbase + lx);
        f32x4 o;
        o.x = fmaf(om, bflo(z2.x), acc.x);
        o.y = fmaf(om, bfhi(z2.x), acc.y);
        o.z = fmaf(om, bflo(z2.y), acc.z);
        o.w = fmaf(om, bfhi(z2.y), acc.w);
        *reinterpret_cast<f32x4*>(yrow + t * 256 + 16 * j + 4 * g) = o;
    }
}

extern "C" void kernel_launch(void* const* d_in, const int* in_sizes, int n_in,
                              void* d_out, int out_size, void* d_ws, size_t ws_size,
                              hipStream_t stream)
{
    const float* x   = (const float*)d_in[0];
    const float* pl  = (const float*)d_in[1];
    const float* lqr = (const float*)d_in[2];
    const float* lqi = (const float*)d_in[3];
    const float* gr  = (const float*)d_in[4];
    const float* gi  = (const float*)d_in[5];
    const float* om  = (const float*)d_in[6];
    float* out = (float*)d_out;

    const size_t needA = (size_t)D_DIM * NK * 64 * 16;   // 5.24 MB of A-fragments
    dim3 grid((B_DIM * D_DIM) / WPB), block(64 * WPB);

    if (ws_size >= needA) {
        ema_mkA<<<dim3(D_DIM), dim3(64), 0, stream>>>(pl, lqr, lqi, gr, gi,
                                                      (uint4*)d_ws);
        ema_fir<true><<<grid, block, 0, stream>>>(x, pl, lqr, lqi, gr, gi, om,
                                                  (const uint4*)d_ws, out);
    } else {
        ema_fir<false><<<grid, block, 0, stream>>>(x, pl, lqr, lqi, gr, gi, om,
                                                   nullptr, out);
    }
}

// Round 8
// 78.214 us; speedup vs baseline: 1.0502x; 1.0502x over previous
//
#include <hip/hip_runtime.h>
#include <hip/hip_bf16.h>
#include <math.h>

#define D_DIM   1024
#define NM      16
#define B_DIM   8
#define L_DIM   4096
#define SCALE_F 0.25f      // sqrt(1/N)
#define NK      5          // MFMA K-steps of 32 -> 160 taps total
#define WPB     4          // waves per block, one (b,d) row per wave
#define NTILE   16         // 4096 / 256 output tiles per row

typedef __attribute__((ext_vector_type(8))) short bf16x8;   // 8 bf16 (4 VGPRs)
typedef __attribute__((ext_vector_type(4))) float f32x4;

union U4 { uint4 u; bf16x8 v; };

__device__ __forceinline__ unsigned rot16(unsigned v) { return (v >> 16) | (v << 16); }
__device__ __forceinline__ unsigned short f2bf(float f) {
    __hip_bfloat16 h = __float2bfloat16(f);               // RNE
    return *reinterpret_cast<unsigned short*>(&h);
}
__device__ __forceinline__ float bflo(unsigned u) { return __uint_as_float(u << 16); }
__device__ __forceinline__ float bfhi(unsigned u) { return __uint_as_float(u & 0xffff0000u); }

// ---------- A-fragment generation ----------
// A[i,t'] = k_d[i + t'], i = lane&15, t' = 32*k + 8*(lane>>4) + e - 15.
// mkA v2: one WAVE per (d,k); per mode: q and q^t0 via exp/sincos once, then
// 7 complex mults walk the 8 consecutive taps (8x fewer transcendentals than
// per-tap evaluation; <=7-deep cmul chain adds ~1e-6 rel err << bf16 4e-3).
__global__ __launch_bounds__(256)
void ema_mkA(const float* __restrict__ p_logit, const float* __restrict__ lqr,
             const float* __restrict__ lqi, const float* __restrict__ gr,
             const float* __restrict__ gi, uint4* __restrict__ wsa)
{
    const int wid  = blockIdx.x * WPB + (threadIdx.x >> 6);   // 0 .. D*NK-1
    const int lane = threadIdx.x & 63;
    const int d    = wid / NK;
    const int k    = wid - d * NK;
    const int i    = lane & 15, g = lane >> 4;
    const int t0   = i - 15 + 32 * k + 8 * g;
    const float t0f = (float)t0;

    float acc[8];
#pragma unroll
    for (int e = 0; e < 8; ++e) acc[e] = 0.0f;

#pragma unroll 1
    for (int n = 0; n < NM; ++n) {
        const int idx = d * NM + n;
        const float pp = 1.0f / (1.0f + __expf(-p_logit[idx]));
        const float CR = gr[idx] * (SCALE_F * pp);
        const float CI = gi[idx] * (SCALE_F * pp);
        const float LR = lqr[idx], LI = lqi[idx];

        float sq, cq; __sincosf(LI, &sq, &cq);
        const float eq = __expf(LR);
        const float qr = eq * cq, qi = eq * sq;          // q

        float s0, c0; __sincosf(t0f * LI, &s0, &c0);
        const float e0 = __expf(t0f * LR);
        float wr = e0 * c0, wi = e0 * s0;                // q^t0 (t0<0 ok)

#pragma unroll
        for (int e = 0; e < 8; ++e) {
            acc[e] = fmaf(CR, wr, fmaf(-CI, wi, acc[e]));
            const float nwr = fmaf(wr, qr, -wi * qi);
            const float nwi = fmaf(wr, qi,  wi * qr);
            wr = nwr; wi = nwi;
        }
    }

    unsigned pk[4];
#pragma unroll
    for (int e = 0; e < 8; ++e) {
        const unsigned b = (t0 + e >= 0) ? (unsigned)f2bf(acc[e]) : 0u;
        if ((e & 1) == 0) pk[e >> 1] = b; else pk[e >> 1] |= b << 16;
    }
    wsa[(size_t)(d * NK + k) * 64 + lane] = make_uint4(pk[0], pk[1], pk[2], pk[3]);
}

// Fallback per-tap A-fragment (used only if ws is too small).
__device__ void compute_afrag(int d, int lane,
                              const float* __restrict__ p_logit,
                              const float* __restrict__ lqr,
                              const float* __restrict__ lqi,
                              const float* __restrict__ gr,
                              const float* __restrict__ gi,
                              bf16x8 (&af)[NK])
{
    float LR[NM], LI[NM], CR[NM], CI[NM];
#pragma unroll
    for (int n = 0; n < NM; ++n) {
        const int idx = d * NM + n;
        const float p = 1.0f / (1.0f + __expf(-p_logit[idx]));
        LR[n] = lqr[idx]; LI[n] = lqi[idx];
        CR[n] = gr[idx] * (SCALE_F * p);
        CI[n] = gi[idx] * (SCALE_F * p);
    }
    const int i = lane & 15, g = lane >> 4;
#pragma unroll
    for (int k = 0; k < NK; ++k) {
        unsigned pk[4] = {0, 0, 0, 0};
#pragma unroll
        for (int e = 0; e < 8; ++e) {
            const int t = i - 15 + 32 * k + 8 * g + e;
            float v = 0.0f;
            if (t >= 0) {
                const float tf = (float)t;
#pragma unroll
                for (int n = 0; n < NM; ++n) {
                    const float er = __expf(tf * LR[n]);
                    float s, c; __sincosf(tf * LI[n], &s, &c);
                    v += er * fmaf(CR[n], c, -CI[n] * s);
                }
            }
            const unsigned b = f2bf(v);
            if ((e & 1) == 0) pk[e >> 1] = b; else pk[e >> 1] |= b << 16;
        }
        U4 u; u.u = make_uint4(pk[0], pk[1], pk[2], pk[3]); af[k] = u.v;
    }
}

// Main kernel: one wave per (b,d) row, 16 tiles of 256 outputs.
// R6 per-tile window math, PLUS a cross-tile software pipeline: the global
// float4 pair for tile t+1 is issued before tile t's ds_read/MFMA compute,
// so the vmcnt wait lands at the top of iteration t+1 and HBM latency hides
// under compute. Double-buffered wave-private LDS window (2x1KB/wave, 8KB/
// block) keeps occupancy at R6 levels (R7's 36KB/block dropped occ to 33%).
template<bool FROM_WS>
__global__ __launch_bounds__(256)
void ema_fir(const float* __restrict__ x,
             const float* __restrict__ p_logit,
             const float* __restrict__ lqr, const float* __restrict__ lqi,
             const float* __restrict__ gr, const float* __restrict__ gi,
             const float* __restrict__ omega,
             const uint4* __restrict__ wsa,
             float* __restrict__ out)
{
    __shared__ __align__(16) unsigned short smem[WPB][2][512];   // 8 KB/block

    const int w    = threadIdx.x >> 6;
    const int lane = threadIdx.x & 63;
    const int row  = blockIdx.x * WPB + w;      // b*D + d
    const int d    = row & (D_DIM - 1);
    const int j    = lane & 15, g = lane >> 4;

    const float* xrow = x   + (size_t)row * L_DIM;
    float*       yrow = out + (size_t)row * L_DIM;
    const float  om   = omega[d];

    bf16x8 af[NK];
    if (FROM_WS) {
#pragma unroll
        for (int k = 0; k < NK; ++k) {
            U4 u; u.u = wsa[(size_t)(d * NK + k) * 64 + lane];
            af[k] = u.v;
        }
    } else {
        compute_afrag(d, lane, p_logit, lqr, lqi, gr, gi, af);
    }

    char* sbase = reinterpret_cast<char*>(&smem[w][0][0]);

    // ---- prologue: tile 0 window [l0-256, l0+255]; lanes 0..31 are the pad ----
    float4 ra, rb;
    {
        const int idx0 = -256 + lane * 8;
        if (idx0 >= 0) {
            ra = *reinterpret_cast<const float4*>(xrow + idx0);
            rb = *reinterpret_cast<const float4*>(xrow + idx0 + 4);
        } else {
            ra = make_float4(0.f, 0.f, 0.f, 0.f);
            rb = make_float4(0.f, 0.f, 0.f, 0.f);
        }
    }

#pragma unroll 2
    for (int t = 0; t < NTILE; ++t) {
        const int p = t & 1;
        char* sb = sbase + p * 1024;

        // ---- cvt + ds_write the current tile's window (waits vmcnt here) ----
        uint4 pk;
        pk.x = (unsigned)f2bf(ra.x) | ((unsigned)f2bf(ra.y) << 16);
        pk.y = (unsigned)f2bf(ra.z) | ((unsigned)f2bf(ra.w) << 16);
        pk.z = (unsigned)f2bf(rb.x) | ((unsigned)f2bf(rb.y) << 16);
        pk.w = (unsigned)f2bf(rb.z) | ((unsigned)f2bf(rb.w) << 16);
        *reinterpret_cast<uint4*>(sb + lane * 16) = pk;

        // ---- issue tile t+1 loads now; consumed next iteration ----
        if (t < NTILE - 1) {
            const int idxn = t * 256 + lane * 8;   // (t+1)*256 - 256 + lane*8
            ra = *reinterpret_cast<const float4*>(xrow + idxn);
            rb = *reinterpret_cast<const float4*>(xrow + idxn + 4);
        }

        // ---- 5 K-steps from LDS: B[t',j] = x[l0+16j-t'] reversed bf16x8 ----
        f32x4 acc = {0.0f, 0.0f, 0.0f, 0.0f};
#pragma unroll
        for (int k = 0; k < NK; ++k) {
            const int boff = 528 + 32 * j - 64 * k - 16 * g;   // 16B aligned
            U4 z; z.u = *reinterpret_cast<const uint4*>(sb + boff);
            uint4 rv;
            rv.x = rot16(z.u.w); rv.y = rot16(z.u.z);
            rv.z = rot16(z.u.y); rv.w = rot16(z.u.x);
            U4 bfv; bfv.u = rv;
            acc = __builtin_amdgcn_mfma_f32_16x16x32_bf16(af[k], bfv.v, acc, 0, 0, 0);
        }

        // ---- epilogue: += omega*x, 4 consecutive outputs per lane ----
        const uint2 z2 = *reinterpret_cast<const uint2*>(sb + 512 + 32 * j + 8 * g);
        f32x4 o;
        o.x = fmaf(om, bflo(z2.x), acc.x);
        o.y = fmaf(om, bfhi(z2.x), acc.y);
        o.z = fmaf(om, bflo(z2.y), acc.z);
        o.w = fmaf(om, bfhi(z2.y), acc.w);
        *reinterpret_cast<f32x4*>(yrow + t * 256 + 16 * j + 4 * g) = o;
    }
}

extern "C" void kernel_launch(void* const* d_in, const int* in_sizes, int n_in,
                              void* d_out, int out_size, void* d_ws, size_t ws_size,
                              hipStream_t stream)
{
    const float* x   = (const float*)d_in[0];
    const float* pl  = (const float*)d_in[1];
    const float* lqr = (const float*)d_in[2];
    const float* lqi = (const float*)d_in[3];
    const float* gr  = (const float*)d_in[4];
    const float* gi  = (const float*)d_in[5];
    const float* om  = (const float*)d_in[6];
    float* out = (float*)d_out;

    const size_t needA = (size_t)D_DIM * NK * 64 * 16;   // 5.24 MB of A-fragments
    dim3 grid((B_DIM * D_DIM) / WPB), block(64 * WPB);

    if (ws_size >= needA) {
        ema_mkA<<<dim3(D_DIM * NK / WPB), dim3(64 * WPB), 0, stream>>>(
            pl, lqr, lqi, gr, gi, (uint4*)d_ws);
        ema_fir<true><<<grid, block, 0, stream>>>(x, pl, lqr, lqi, gr, gi, om,
                                                  (const uint4*)d_ws, out);
    } else {
        ema_fir<false><<<grid, block, 0, stream>>>(x, pl, lqr, lqi, gr, gi, om,
                                                   nullptr, out);
    }
}

// Round 9
// 68.525 us; speedup vs baseline: 1.1986x; 1.1414x over previous
//
#include <hip/hip_runtime.h>
#include <hip/hip_bf16.h>
#include <math.h>

#define D_DIM   1024
#define NM      16
#define B_DIM   8
#define L_DIM   4096
#define SCALE_F 0.25f      // sqrt(1/N)
#define NK      5          // MFMA K-steps of 32 -> 160 taps total
#define WPB     4          // waves per block, one (b,d) row per wave
#define NSUP    4          // super-tiles per row
#define RING    4096       // ring bytes per wave: 2048 bf16 = 2 windows

typedef __attribute__((ext_vector_type(8))) short bf16x8;   // 8 bf16 (4 VGPRs)
typedef __attribute__((ext_vector_type(4))) float f32x4;

union U4 { uint4 u; bf16x8 v; };

__device__ __forceinline__ unsigned rot16(unsigned v) { return (v >> 16) | (v << 16); }
__device__ __forceinline__ unsigned short f2bf(float f) {
    __hip_bfloat16 h = __float2bfloat16(f);               // RNE
    return *reinterpret_cast<unsigned short*>(&h);
}
__device__ __forceinline__ float bflo(unsigned u) { return __uint_as_float(u << 16); }
__device__ __forceinline__ float bfhi(unsigned u) { return __uint_as_float(u & 0xffff0000u); }

// ---------- A-fragment generation (unchanged from R8) ----------
__global__ __launch_bounds__(256)
void ema_mkA(const float* __restrict__ p_logit, const float* __restrict__ lqr,
             const float* __restrict__ lqi, const float* __restrict__ gr,
             const float* __restrict__ gi, uint4* __restrict__ wsa)
{
    const int wid  = blockIdx.x * WPB + (threadIdx.x >> 6);   // 0 .. D*NK-1
    const int lane = threadIdx.x & 63;
    const int d    = wid / NK;
    const int k    = wid - d * NK;
    const int i    = lane & 15, g = lane >> 4;
    const int t0   = i - 15 + 32 * k + 8 * g;
    const float t0f = (float)t0;

    float acc[8];
#pragma unroll
    for (int e = 0; e < 8; ++e) acc[e] = 0.0f;

#pragma unroll 1
    for (int n = 0; n < NM; ++n) {
        const int idx = d * NM + n;
        const float pp = 1.0f / (1.0f + __expf(-p_logit[idx]));
        const float CR = gr[idx] * (SCALE_F * pp);
        const float CI = gi[idx] * (SCALE_F * pp);
        const float LR = lqr[idx], LI = lqi[idx];

        float sq, cq; __sincosf(LI, &sq, &cq);
        const float eq = __expf(LR);
        const float qr = eq * cq, qi = eq * sq;          // q
        float s0, c0; __sincosf(t0f * LI, &s0, &c0);
        const float e0 = __expf(t0f * LR);
        float wr = e0 * c0, wi = e0 * s0;                // q^t0

#pragma unroll
        for (int e = 0; e < 8; ++e) {
            acc[e] = fmaf(CR, wr, fmaf(-CI, wi, acc[e]));
            const float nwr = fmaf(wr, qr, -wi * qi);
            const float nwi = fmaf(wr, qi,  wi * qr);
            wr = nwr; wi = nwi;
        }
    }

    unsigned pk[4];
#pragma unroll
    for (int e = 0; e < 8; ++e) {
        const unsigned b = (t0 + e >= 0) ? (unsigned)f2bf(acc[e]) : 0u;
        if ((e & 1) == 0) pk[e >> 1] = b; else pk[e >> 1] |= b << 16;
    }
    wsa[(size_t)(d * NK + k) * 64 + lane] = make_uint4(pk[0], pk[1], pk[2], pk[3]);
}

// Fallback per-tap A-fragment (only if ws too small).
__device__ void compute_afrag(int d, int lane,
                              const float* __restrict__ p_logit,
                              const float* __restrict__ lqr,
                              const float* __restrict__ lqi,
                              const float* __restrict__ gr,
                              const float* __restrict__ gi,
                              bf16x8 (&af)[NK])
{
    float LR[NM], LI[NM], CR[NM], CI[NM];
#pragma unroll
    for (int n = 0; n < NM; ++n) {
        const int idx = d * NM + n;
        const float p = 1.0f / (1.0f + __expf(-p_logit[idx]));
        LR[n] = lqr[idx]; LI[n] = lqi[idx];
        CR[n] = gr[idx] * (SCALE_F * p);
        CI[n] = gi[idx] * (SCALE_F * p);
    }
    const int i = lane & 15, g = lane >> 4;
#pragma unroll
    for (int k = 0; k < NK; ++k) {
        unsigned pk[4] = {0, 0, 0, 0};
#pragma unroll
        for (int e = 0; e < 8; ++e) {
            const int t = i - 15 + 32 * k + 8 * g + e;
            float v = 0.0f;
            if (t >= 0) {
                const float tf = (float)t;
#pragma unroll
                for (int n = 0; n < NM; ++n) {
                    const float er = __expf(tf * LR[n]);
                    float s, c; __sincosf(tf * LI[n], &s, &c);
                    v += er * fmaf(CR[n], c, -CI[n] * s);
                }
            }
            const unsigned b = f2bf(v);
            if ((e & 1) == 0) pk[e >> 1] = b; else pk[e >> 1] |= b << 16;
        }
        U4 u; u.u = make_uint4(pk[0], pk[1], pk[2], pk[3]); af[k] = u.v;
    }
}

// Main kernel: one wave per (b,d) row. SUPER-TILE structure: per step stage
// 1024 NEW x elems into a 4KB ring (4 float4 loads/lane-group = 4-deep MLP,
// one vmcnt wait per 4 tiles), compute 4 tiles (20 ds_read+MFMA, 4 indep acc
// chains), then burst 4 dwordx4 stores = 4KB contiguous per wave. Each x elem
// is read from global exactly ONCE (ring reuses the 256-elem left context).
// R6/R7/R8 all ~80us with tiny per-wave MLP -> memory-queue equilibrium;
// this quadruples transaction depth and halves requested reads.
template<bool FROM_WS>
__global__ __launch_bounds__(256)
void ema_fir(const float* __restrict__ x,
             const float* __restrict__ p_logit,
             const float* __restrict__ lqr, const float* __restrict__ lqi,
             const float* __restrict__ gr, const float* __restrict__ gi,
             const float* __restrict__ omega,
             const uint4* __restrict__ wsa,
             float* __restrict__ out)
{
    __shared__ __align__(16) char smem[WPB][RING];   // 16 KB/block

    const int w    = threadIdx.x >> 6;
    const int lane = threadIdx.x & 63;
    const int row  = blockIdx.x * WPB + w;      // b*D + d
    const int d    = row & (D_DIM - 1);
    const int j    = lane & 15, g = lane >> 4;

    const float* xrow = x   + (size_t)row * L_DIM;
    float*       yrow = out + (size_t)row * L_DIM;
    const float  om   = omega[d];

    bf16x8 af[NK];
    if (FROM_WS) {
#pragma unroll
        for (int k = 0; k < NK; ++k) {
            U4 u; u.u = wsa[(size_t)(d * NK + k) * 64 + lane];
            af[k] = u.v;
        }
    } else {
        compute_afrag(d, lane, p_logit, lqr, lqi, gr, gi, af);
    }

    char* sb = smem[w];

    // ---- zero pad: x[-256..-1] -> ring bytes [0,512) ----
    *reinterpret_cast<uint2*>(sb + lane * 8) = make_uint2(0u, 0u);

    // ---- prefetch super-tile 0: 16 consecutive floats per lane ----
    float4 r[4];
#pragma unroll
    for (int v = 0; v < 4; ++v)
        r[v] = *reinterpret_cast<const float4*>(xrow + lane * 16 + 4 * v);

#pragma unroll
    for (int s = 0; s < NSUP; ++s) {
        // ---- pack 16 floats -> 16 bf16, 2 uint4 ds_writes (x-linear in ring) ----
        // x[l] lives at ring byte (512 + 2l) & 4095; this lane covers
        // l = 1024s + lane*16 + [0,16). No write crosses the ring edge
        // (offsets are multiples of 32, 32B writes).
        unsigned pk[8];
#pragma unroll
        for (int v = 0; v < 4; ++v) {
            pk[2 * v + 0] = (unsigned)f2bf(r[v].x) | ((unsigned)f2bf(r[v].y) << 16);
            pk[2 * v + 1] = (unsigned)f2bf(r[v].z) | ((unsigned)f2bf(r[v].w) << 16);
        }
        const int wbase = (512 + 2048 * s + lane * 32) & (RING - 1);
        *reinterpret_cast<uint4*>(sb + wbase)      = make_uint4(pk[0], pk[1], pk[2], pk[3]);
        *reinterpret_cast<uint4*>(sb + wbase + 16) = make_uint4(pk[4], pk[5], pk[6], pk[7]);

        // ---- issue next super-tile's loads now (consumed next iteration) ----
        if (s < NSUP - 1) {
#pragma unroll
            for (int v = 0; v < 4; ++v)
                r[v] = *reinterpret_cast<const float4*>(
                    xrow + (s + 1) * 1024 + lane * 16 + 4 * v);
        }

        // ---- compute 4 tiles from the ring (4 independent MFMA chains) ----
        f32x4 acc[4];
#pragma unroll
        for (int tt = 0; tt < 4; ++tt) {
            const int t = 4 * s + tt;
            acc[tt].x = 0.0f; acc[tt].y = 0.0f; acc[tt].z = 0.0f; acc[tt].w = 0.0f;
#pragma unroll
            for (int k = 0; k < NK; ++k) {
                const int boff = (512 * t + 528 + 32 * j - 64 * k - 16 * g) & (RING - 1);
                U4 z; z.u = *reinterpret_cast<const uint4*>(sb + boff);
                uint4 rv;
                rv.x = rot16(z.u.w); rv.y = rot16(z.u.z);
                rv.z = rot16(z.u.y); rv.w = rot16(z.u.x);
                U4 bfv; bfv.u = rv;
                acc[tt] = __builtin_amdgcn_mfma_f32_16x16x32_bf16(af[k], bfv.v,
                                                                  acc[tt], 0, 0, 0);
            }
            const int lx = (512 * t + 512 + 32 * j + 8 * g) & (RING - 1);
            const uint2 z2 = *reinterpret_cast<const uint2*>(sb + lx);
            acc[tt].x = fmaf(om, bflo(z2.x), acc[tt].x);
            acc[tt].y = fmaf(om, bfhi(z2.x), acc[tt].y);
            acc[tt].z = fmaf(om, bflo(z2.y), acc[tt].z);
            acc[tt].w = fmaf(om, bfhi(z2.y), acc[tt].w);
        }

        // ---- burst store: 4 dwordx4/lane, wave covers 4KB contiguous ----
#pragma unroll
        for (int tt = 0; tt < 4; ++tt)
            *reinterpret_cast<f32x4*>(yrow + (4 * s + tt) * 256 + 16 * j + 4 * g) = acc[tt];
    }
}

extern "C" void kernel_launch(void* const* d_in, const int* in_sizes, int n_in,
                              void* d_out, int out_size, void* d_ws, size_t ws_size,
                              hipStream_t stream)
{
    const float* x   = (const float*)d_in[0];
    const float* pl  = (const float*)d_in[1];
    const float* lqr = (const float*)d_in[2];
    const float* lqi = (const float*)d_in[3];
    const float* gr  = (const float*)d_in[4];
    const float* gi  = (const float*)d_in[5];
    const float* om  = (const float*)d_in[6];
    float* out = (float*)d_out;

    const size_t needA = (size_t)D_DIM * NK * 64 * 16;   // 5.24 MB of A-fragments
    dim3 grid((B_DIM * D_DIM) / WPB), block(64 * WPB);

    if (ws_size >= needA) {
        ema_mkA<<<dim3(D_DIM * NK / WPB), dim3(64 * WPB), 0, stream>>>(
            pl, lqr, lqi, gr, gi, (uint4*)d_ws);
        ema_fir<true><<<grid, block, 0, stream>>>(x, pl, lqr, lqi, gr, gi, om,
                                                  (const uint4*)d_ws, out);
    } else {
        ema_fir<false><<<grid, block, 0, stream>>>(x, pl, lqr, lqi, gr, gi, om,
                                                   nullptr, out);
    }
}

// Round 10
// 60.861 us; speedup vs baseline: 1.3496x; 1.1259x over previous
//
#include <hip/hip_runtime.h>
#include <hip/hip_bf16.h>
#include <math.h>

#define D_DIM   1024
#define NM      16
#define B_DIM   8
#define L_DIM   4096
#define SCALE_F 0.25f      // sqrt(1/N)
#define NK      5          // MFMA K-steps of 32 -> 160 taps total
#define WPB     4          // waves per block
#define NSUP    2          // super-tiles per wave (half a row)
#define RING    4096       // ring bytes per wave: 2048 bf16

typedef __attribute__((ext_vector_type(8))) short bf16x8;   // 8 bf16 (4 VGPRs)
typedef __attribute__((ext_vector_type(4))) float f32x4;

union U4 { uint4 u; bf16x8 v; };

__device__ __forceinline__ unsigned rot16(unsigned v) { return (v >> 16) | (v << 16); }
__device__ __forceinline__ unsigned short f2bf(float f) {
    __hip_bfloat16 h = __float2bfloat16(f);               // RNE
    return *reinterpret_cast<unsigned short*>(&h);
}
__device__ __forceinline__ float bflo(unsigned u) { return __uint_as_float(u << 16); }
__device__ __forceinline__ float bfhi(unsigned u) { return __uint_as_float(u & 0xffff0000u); }

// ---------- A-fragment generation (unchanged from R8/R9) ----------
__global__ __launch_bounds__(256)
void ema_mkA(const float* __restrict__ p_logit, const float* __restrict__ lqr,
             const float* __restrict__ lqi, const float* __restrict__ gr,
             const float* __restrict__ gi, uint4* __restrict__ wsa)
{
    const int wid  = blockIdx.x * WPB + (threadIdx.x >> 6);   // 0 .. D*NK-1
    const int lane = threadIdx.x & 63;
    const int d    = wid / NK;
    const int k    = wid - d * NK;
    const int i    = lane & 15, g = lane >> 4;
    const int t0   = i - 15 + 32 * k + 8 * g;
    const float t0f = (float)t0;

    float acc[8];
#pragma unroll
    for (int e = 0; e < 8; ++e) acc[e] = 0.0f;

#pragma unroll 1
    for (int n = 0; n < NM; ++n) {
        const int idx = d * NM + n;
        const float pp = 1.0f / (1.0f + __expf(-p_logit[idx]));
        const float CR = gr[idx] * (SCALE_F * pp);
        const float CI = gi[idx] * (SCALE_F * pp);
        const float LR = lqr[idx], LI = lqi[idx];

        float sq, cq; __sincosf(LI, &sq, &cq);
        const float eq = __expf(LR);
        const float qr = eq * cq, qi = eq * sq;          // q
        float s0, c0; __sincosf(t0f * LI, &s0, &c0);
        const float e0 = __expf(t0f * LR);
        float wr = e0 * c0, wi = e0 * s0;                // q^t0

#pragma unroll
        for (int e = 0; e < 8; ++e) {
            acc[e] = fmaf(CR, wr, fmaf(-CI, wi, acc[e]));
            const float nwr = fmaf(wr, qr, -wi * qi);
            const float nwi = fmaf(wr, qi,  wi * qr);
            wr = nwr; wi = nwi;
        }
    }

    unsigned pk[4];
#pragma unroll
    for (int e = 0; e < 8; ++e) {
        const unsigned b = (t0 + e >= 0) ? (unsigned)f2bf(acc[e]) : 0u;
        if ((e & 1) == 0) pk[e >> 1] = b; else pk[e >> 1] |= b << 16;
    }
    wsa[(size_t)(d * NK + k) * 64 + lane] = make_uint4(pk[0], pk[1], pk[2], pk[3]);
}

// Fallback per-tap A-fragment (only if ws too small).
__device__ void compute_afrag(int d, int lane,
                              const float* __restrict__ p_logit,
                              const float* __restrict__ lqr,
                              const float* __restrict__ lqi,
                              const float* __restrict__ gr,
                              const float* __restrict__ gi,
                              bf16x8 (&af)[NK])
{
    float LR[NM], LI[NM], CR[NM], CI[NM];
#pragma unroll
    for (int n = 0; n < NM; ++n) {
        const int idx = d * NM + n;
        const float p = 1.0f / (1.0f + __expf(-p_logit[idx]));
        LR[n] = lqr[idx]; LI[n] = lqi[idx];
        CR[n] = gr[idx] * (SCALE_F * p);
        CI[n] = gi[idx] * (SCALE_F * p);
    }
    const int i = lane & 15, g = lane >> 4;
#pragma unroll
    for (int k = 0; k < NK; ++k) {
        unsigned pk[4] = {0, 0, 0, 0};
#pragma unroll
        for (int e = 0; e < 8; ++e) {
            const int t = i - 15 + 32 * k + 8 * g + e;
            float v = 0.0f;
            if (t >= 0) {
                const float tf = (float)t;
#pragma unroll
                for (int n = 0; n < NM; ++n) {
                    const float er = __expf(tf * LR[n]);
                    float s, c; __sincosf(tf * LI[n], &s, &c);
                    v += er * fmaf(CR[n], c, -CI[n] * s);
                }
            }
            const unsigned b = f2bf(v);
            if ((e & 1) == 0) pk[e >> 1] = b; else pk[e >> 1] |= b << 16;
        }
        U4 u; u.u = make_uint4(pk[0], pk[1], pk[2], pk[3]); af[k] = u.v;
    }
}

// Main kernel v5: TWO waves per (b,d) row, each owning a 2048-sample half-row
// (2 super-tiles). Doubles independent per-CU chains and halves each wave's
// serial length vs R9 (R9: whole-row waves, 68.5us, all counters idle ->
// latency-equilibrium). half=1 waves stage their real 256-sample left context.
// Ring mapping, boff math, MFMA fragments byte-identical to R9.
// Output uses nontemporal stores (never re-read -> don't pollute L2/L3).
template<bool FROM_WS>
__global__ __launch_bounds__(256)
void ema_fir(const float* __restrict__ x,
             const float* __restrict__ p_logit,
             const float* __restrict__ lqr, const float* __restrict__ lqi,
             const float* __restrict__ gr, const float* __restrict__ gi,
             const float* __restrict__ omega,
             const uint4* __restrict__ wsa,
             float* __restrict__ out)
{
    __shared__ __align__(16) char smem[WPB][RING];   // 16 KB/block

    const int w    = threadIdx.x >> 6;
    const int lane = threadIdx.x & 63;
    const int wid  = blockIdx.x * WPB + w;      // 0 .. 2*B*D-1
    const int row  = wid >> 1;                  // b*D + d
    const int half = wid & 1;                   // which half-row
    const int d    = row & (D_DIM - 1);
    const int j    = lane & 15, g = lane >> 4;

    const float* xbase = x   + (size_t)row * L_DIM + half * 2048;
    float*       ybase = out + (size_t)row * L_DIM + half * 2048;
    const float  om    = omega[d];

    bf16x8 af[NK];
    if (FROM_WS) {
#pragma unroll
        for (int k = 0; k < NK; ++k) {
            U4 u; u.u = wsa[(size_t)(d * NK + k) * 64 + lane];
            af[k] = u.v;
        }
    } else {
        compute_afrag(d, lane, p_logit, lqr, lqi, gr, gi, af);
    }

    char* sb = smem[w];

    // ---- context x[-256..-1] -> ring bytes [0,512): zeros (half 0) or real ----
    if (half == 0) {
        *reinterpret_cast<uint2*>(sb + lane * 8) = make_uint2(0u, 0u);
    } else {
        const float4 c4 = *reinterpret_cast<const float4*>(xbase - 256 + lane * 4);
        uint2 cpk;
        cpk.x = (unsigned)f2bf(c4.x) | ((unsigned)f2bf(c4.y) << 16);
        cpk.y = (unsigned)f2bf(c4.z) | ((unsigned)f2bf(c4.w) << 16);
        *reinterpret_cast<uint2*>(sb + lane * 8) = cpk;
    }

    // ---- prefetch super-tile 0: 16 consecutive floats per lane ----
    float4 r[4];
#pragma unroll
    for (int v = 0; v < 4; ++v)
        r[v] = *reinterpret_cast<const float4*>(xbase + lane * 16 + 4 * v);

#pragma unroll
    for (int s = 0; s < NSUP; ++s) {
        // ---- pack 16 floats -> 16 bf16, 2 uint4 ds_writes (x-linear in ring) ----
        unsigned pk[8];
#pragma unroll
        for (int v = 0; v < 4; ++v) {
            pk[2 * v + 0] = (unsigned)f2bf(r[v].x) | ((unsigned)f2bf(r[v].y) << 16);
            pk[2 * v + 1] = (unsigned)f2bf(r[v].z) | ((unsigned)f2bf(r[v].w) << 16);
        }
        const int wbase = (512 + 2048 * s + lane * 32) & (RING - 1);
        *reinterpret_cast<uint4*>(sb + wbase)      = make_uint4(pk[0], pk[1], pk[2], pk[3]);
        *reinterpret_cast<uint4*>(sb + wbase + 16) = make_uint4(pk[4], pk[5], pk[6], pk[7]);

        // ---- issue next super-tile's loads now (consumed next iteration) ----
        if (s < NSUP - 1) {
#pragma unroll
            for (int v = 0; v < 4; ++v)
                r[v] = *reinterpret_cast<const float4*>(
                    xbase + (s + 1) * 1024 + lane * 16 + 4 * v);
        }

        // ---- compute 4 tiles from the ring (4 independent MFMA chains) ----
        f32x4 acc[4];
#pragma unroll
        for (int tt = 0; tt < 4; ++tt) {
            const int t = 4 * s + tt;               // local tile index 0..7
            acc[tt].x = 0.0f; acc[tt].y = 0.0f; acc[tt].z = 0.0f; acc[tt].w = 0.0f;
#pragma unroll
            for (int k = 0; k < NK; ++k) {
                const int boff = (512 * t + 528 + 32 * j - 64 * k - 16 * g) & (RING - 1);
                U4 z; z.u = *reinterpret_cast<const uint4*>(sb + boff);
                uint4 rv;
                rv.x = rot16(z.u.w); rv.y = rot16(z.u.z);
                rv.z = rot16(z.u.y); rv.w = rot16(z.u.x);
                U4 bfv; bfv.u = rv;
                acc[tt] = __builtin_amdgcn_mfma_f32_16x16x32_bf16(af[k], bfv.v,
                                                                  acc[tt], 0, 0, 0);
            }
            const int lx = (512 * t + 512 + 32 * j + 8 * g) & (RING - 1);
            const uint2 z2 = *reinterpret_cast<const uint2*>(sb + lx);
            acc[tt].x = fmaf(om, bflo(z2.x), acc[tt].x);
            acc[tt].y = fmaf(om, bfhi(z2.x), acc[tt].y);
            acc[tt].z = fmaf(om, bflo(z2.y), acc[tt].z);
            acc[tt].w = fmaf(om, bfhi(z2.y), acc[tt].w);
        }

        // ---- burst nontemporal store: wave covers 4KB contiguous ----
#pragma unroll
        for (int tt = 0; tt < 4; ++tt)
            __builtin_nontemporal_store(acc[tt],
                reinterpret_cast<f32x4*>(ybase + (4 * s + tt) * 256 + 16 * j + 4 * g));
    }
}

extern "C" void kernel_launch(void* const* d_in, const int* in_sizes, int n_in,
                              void* d_out, int out_size, void* d_ws, size_t ws_size,
                              hipStream_t stream)
{
    const float* x   = (const float*)d_in[0];
    const float* pl  = (const float*)d_in[1];
    const float* lqr = (const float*)d_in[2];
    const float* lqi = (const float*)d_in[3];
    const float* gr  = (const float*)d_in[4];
    const float* gi  = (const float*)d_in[5];
    const float* om  = (const float*)d_in[6];
    float* out = (float*)d_out;

    const size_t needA = (size_t)D_DIM * NK * 64 * 16;   // 5.24 MB of A-fragments
    dim3 grid((2 * B_DIM * D_DIM) / WPB), block(64 * WPB);   // 2 waves per row

    if (ws_size >= needA) {
        ema_mkA<<<dim3(D_DIM * NK / WPB), dim3(64 * WPB), 0, stream>>>(
            pl, lqr, lqi, gr, gi, (uint4*)d_ws);
        ema_fir<true><<<grid, block, 0, stream>>>(x, pl, lqr, lqi, gr, gi, om,
                                                  (const uint4*)d_ws, out);
    } else {
        ema_fir<false><<<grid, block, 0, stream>>>(x, pl, lqr, lqi, gr, gi, om,
                                                   nullptr, out);
    }
}

// Round 11
// 60.030 us; speedup vs baseline: 1.3683x; 1.0138x over previous
//
#include <hip/hip_runtime.h>
#include <hip/hip_bf16.h>
#include <math.h>

#define D_DIM   1024
#define NM      16
#define B_DIM   8
#define L_DIM   4096
#define SCALE_F 0.25f      // sqrt(1/N)
#define NK      5          // MFMA K-steps of 32 -> 160 taps total
#define WPB     4          // waves per block
#define TPW     4          // tiles per wave (one super-tile)
#define LBUF    2560       // LDS bytes per wave: 256-elem context + 1024 elems

typedef __attribute__((ext_vector_type(8))) short bf16x8;   // 8 bf16 (4 VGPRs)
typedef __attribute__((ext_vector_type(4))) float f32x4;

union U4 { uint4 u; bf16x8 v; };

__device__ __forceinline__ unsigned rot16(unsigned v) { return (v >> 16) | (v << 16); }
__device__ __forceinline__ unsigned short f2bf(float f) {
    __hip_bfloat16 h = __float2bfloat16(f);               // RNE
    return *reinterpret_cast<unsigned short*>(&h);
}
__device__ __forceinline__ float bflo(unsigned u) { return __uint_as_float(u << 16); }
__device__ __forceinline__ float bfhi(unsigned u) { return __uint_as_float(u & 0xffff0000u); }
// 16B-slot XOR swizzle, applied on BOTH ds_write and ds_read: slots v and v+8
// previously shared a bank group (the 1.77M-cycle conflict in R10).
__device__ __forceinline__ int swz(int a) { return a ^ (((a >> 7) & 7) << 4); }

// ---------- A-fragment generation (unchanged from R8-R10) ----------
__global__ __launch_bounds__(256)
void ema_mkA(const float* __restrict__ p_logit, const float* __restrict__ lqr,
             const float* __restrict__ lqi, const float* __restrict__ gr,
             const float* __restrict__ gi, uint4* __restrict__ wsa)
{
    const int wid  = blockIdx.x * WPB + (threadIdx.x >> 6);   // 0 .. D*NK-1
    const int lane = threadIdx.x & 63;
    const int d    = wid / NK;
    const int k    = wid - d * NK;
    const int i    = lane & 15, g = lane >> 4;
    const int t0   = i - 15 + 32 * k + 8 * g;
    const float t0f = (float)t0;

    float acc[8];
#pragma unroll
    for (int e = 0; e < 8; ++e) acc[e] = 0.0f;

#pragma unroll 1
    for (int n = 0; n < NM; ++n) {
        const int idx = d * NM + n;
        const float pp = 1.0f / (1.0f + __expf(-p_logit[idx]));
        const float CR = gr[idx] * (SCALE_F * pp);
        const float CI = gi[idx] * (SCALE_F * pp);
        const float LR = lqr[idx], LI = lqi[idx];

        float sq, cq; __sincosf(LI, &sq, &cq);
        const float eq = __expf(LR);
        const float qr = eq * cq, qi = eq * sq;          // q
        float s0, c0; __sincosf(t0f * LI, &s0, &c0);
        const float e0 = __expf(t0f * LR);
        float wr = e0 * c0, wi = e0 * s0;                // q^t0

#pragma unroll
        for (int e = 0; e < 8; ++e) {
            acc[e] = fmaf(CR, wr, fmaf(-CI, wi, acc[e]));
            const float nwr = fmaf(wr, qr, -wi * qi);
            const float nwi = fmaf(wr, qi,  wi * qr);
            wr = nwr; wi = nwi;
        }
    }

    unsigned pk[4];
#pragma unroll
    for (int e = 0; e < 8; ++e) {
        const unsigned b = (t0 + e >= 0) ? (unsigned)f2bf(acc[e]) : 0u;
        if ((e & 1) == 0) pk[e >> 1] = b; else pk[e >> 1] |= b << 16;
    }
    wsa[(size_t)(d * NK + k) * 64 + lane] = make_uint4(pk[0], pk[1], pk[2], pk[3]);
}

// Fallback per-tap A-fragment (only if ws too small).
__device__ void compute_afrag(int d, int lane,
                              const float* __restrict__ p_logit,
                              const float* __restrict__ lqr,
                              const float* __restrict__ lqi,
                              const float* __restrict__ gr,
                              const float* __restrict__ gi,
                              bf16x8 (&af)[NK])
{
    float LR[NM], LI[NM], CR[NM], CI[NM];
#pragma unroll
    for (int n = 0; n < NM; ++n) {
        const int idx = d * NM + n;
        const float p = 1.0f / (1.0f + __expf(-p_logit[idx]));
        LR[n] = lqr[idx]; LI[n] = lqi[idx];
        CR[n] = gr[idx] * (SCALE_F * p);
        CI[n] = gi[idx] * (SCALE_F * p);
    }
    const int i = lane & 15, g = lane >> 4;
#pragma unroll
    for (int k = 0; k < NK; ++k) {
        unsigned pk[4] = {0, 0, 0, 0};
#pragma unroll
        for (int e = 0; e < 8; ++e) {
            const int t = i - 15 + 32 * k + 8 * g + e;
            float v = 0.0f;
            if (t >= 0) {
                const float tf = (float)t;
#pragma unroll
                for (int n = 0; n < NM; ++n) {
                    const float er = __expf(tf * LR[n]);
                    float s, c; __sincosf(tf * LI[n], &s, &c);
                    v += er * fmaf(CR[n], c, -CI[n] * s);
                }
            }
            const unsigned b = f2bf(v);
            if ((e & 1) == 0) pk[e >> 1] = b; else pk[e >> 1] |= b << 16;
        }
        U4 u; u.u = make_uint4(pk[0], pk[1], pk[2], pk[3]); af[k] = u.v;
    }
}

// Main kernel v6: FOUR waves per (b,d) row, each owning ONE 1024-sample
// super-tile -- fully straight-line (no loop-carried state). Per wave:
// {context + 4 float4 + af loads all in flight} -> pack + 2 swizzled
// ds_write_b128 -> 20 swizzled ds_read+MFMA (4 indep acc chains) -> 4KB
// contiguous nontemporal store burst. 2x independent chains vs R10, half the
// serial length; LDS XOR-swizzle kills R10's 1.77M-cycle read conflicts.
// Window math identical to R9/R10 with local t in [0,3] (no ring wrap:
// boff in [224,2544] within the 2560B linear window -- no mask needed).
template<bool FROM_WS>
__global__ __launch_bounds__(256)
void ema_fir(const float* __restrict__ x,
             const float* __restrict__ p_logit,
             const float* __restrict__ lqr, const float* __restrict__ lqi,
             const float* __restrict__ gr, const float* __restrict__ gi,
             const float* __restrict__ omega,
             const uint4* __restrict__ wsa,
             float* __restrict__ out)
{
    __shared__ __align__(16) char smem[WPB][LBUF];   // 10 KB/block

    const int w    = threadIdx.x >> 6;
    const int lane = threadIdx.x & 63;
    const int wid  = blockIdx.x * WPB + w;      // 0 .. 4*B*D-1
    const int row  = wid >> 2;                  // b*D + d
    const int qtr  = wid & 3;                   // which quarter-row
    const int d    = row & (D_DIM - 1);
    const int j    = lane & 15, g = lane >> 4;

    const float* xbase = x   + (size_t)row * L_DIM + qtr * 1024;
    float*       ybase = out + (size_t)row * L_DIM + qtr * 1024;

    // ---- issue ALL global loads up front (context, super-tile, omega) ----
    float4 c4 = make_float4(0.f, 0.f, 0.f, 0.f);
    if (qtr != 0)
        c4 = *reinterpret_cast<const float4*>(xbase - 256 + lane * 4);

    float4 r[4];
#pragma unroll
    for (int v = 0; v < 4; ++v)
        r[v] = *reinterpret_cast<const float4*>(xbase + lane * 16 + 4 * v);

    const float om = omega[d];

    bf16x8 af[NK];
    if (FROM_WS) {
#pragma unroll
        for (int k = 0; k < NK; ++k) {
            U4 u; u.u = wsa[(size_t)(d * NK + k) * 64 + lane];
            af[k] = u.v;
        }
    } else {
        compute_afrag(d, lane, p_logit, lqr, lqi, gr, gi, af);
    }

    char* sb = smem[w];

    // ---- context x[-256..-1] -> bytes [0,512) (swizzled) ----
    {
        uint2 cpk;
        cpk.x = (unsigned)f2bf(c4.x) | ((unsigned)f2bf(c4.y) << 16);
        cpk.y = (unsigned)f2bf(c4.z) | ((unsigned)f2bf(c4.w) << 16);
        *reinterpret_cast<uint2*>(sb + swz(lane * 8)) = cpk;
    }

    // ---- stage 1024 elems: x[l] at byte 512 + 2l (swizzled) ----
    {
        unsigned pk[8];
#pragma unroll
        for (int v = 0; v < 4; ++v) {
            pk[2 * v + 0] = (unsigned)f2bf(r[v].x) | ((unsigned)f2bf(r[v].y) << 16);
            pk[2 * v + 1] = (unsigned)f2bf(r[v].z) | ((unsigned)f2bf(r[v].w) << 16);
        }
        const int wbase = 512 + lane * 32;
        *reinterpret_cast<uint4*>(sb + swz(wbase))      = make_uint4(pk[0], pk[1], pk[2], pk[3]);
        *reinterpret_cast<uint4*>(sb + swz(wbase + 16)) = make_uint4(pk[4], pk[5], pk[6], pk[7]);
    }

    // ---- 4 tiles, 4 independent MFMA chains, all from LDS ----
    f32x4 acc[TPW];
#pragma unroll
    for (int tt = 0; tt < TPW; ++tt) {
        acc[tt].x = 0.0f; acc[tt].y = 0.0f; acc[tt].z = 0.0f; acc[tt].w = 0.0f;
#pragma unroll
        for (int k = 0; k < NK; ++k) {
            const int boff = 512 * tt + 528 + 32 * j - 64 * k - 16 * g;  // [224,2544]
            U4 z; z.u = *reinterpret_cast<const uint4*>(sb + swz(boff));
            uint4 rv;
            rv.x = rot16(z.u.w); rv.y = rot16(z.u.z);
            rv.z = rot16(z.u.y); rv.w = rot16(z.u.x);
            U4 bfv; bfv.u = rv;
            acc[tt] = __builtin_amdgcn_mfma_f32_16x16x32_bf16(af[k], bfv.v,
                                                              acc[tt], 0, 0, 0);
        }
        const int lx = 512 * tt + 512 + 32 * j + 8 * g;    // 8B-aligned, <=2552
        const uint2 z2 = *reinterpret_cast<const uint2*>(sb + swz(lx));
        acc[tt].x = fmaf(om, bflo(z2.x), acc[tt].x);
        acc[tt].y = fmaf(om, bfhi(z2.x), acc[tt].y);
        acc[tt].z = fmaf(om, bflo(z2.y), acc[tt].z);
        acc[tt].w = fmaf(om, bfhi(z2.y), acc[tt].w);
    }

    // ---- burst nontemporal store: wave covers 4KB contiguous ----
#pragma unroll
    for (int tt = 0; tt < TPW; ++tt)
        __builtin_nontemporal_store(acc[tt],
            reinterpret_cast<f32x4*>(ybase + tt * 256 + 16 * j + 4 * g));
}

extern "C" void kernel_launch(void* const* d_in, const int* in_sizes, int n_in,
                              void* d_out, int out_size, void* d_ws, size_t ws_size,
                              hipStream_t stream)
{
    const float* x   = (const float*)d_in[0];
    const float* pl  = (const float*)d_in[1];
    const float* lqr = (const float*)d_in[2];
    const float* lqi = (const float*)d_in[3];
    const float* gr  = (const float*)d_in[4];
    const float* gi  = (const float*)d_in[5];
    const float* om  = (const float*)d_in[6];
    float* out = (float*)d_out;

    const size_t needA = (size_t)D_DIM * NK * 64 * 16;   // 5.24 MB of A-fragments
    dim3 grid((4 * B_DIM * D_DIM) / WPB), block(64 * WPB);   // 4 waves per row

    if (ws_size >= needA) {
        ema_mkA<<<dim3(D_DIM * NK / WPB), dim3(64 * WPB), 0, stream>>>(
            pl, lqr, lqi, gr, gi, (uint4*)d_ws);
        ema_fir<true><<<grid, block, 0, stream>>>(x, pl, lqr, lqi, gr, gi, om,
                                                  (const uint4*)d_ws, out);
    } else {
        ema_fir<false><<<grid, block, 0, stream>>>(x, pl, lqr, lqi, gr, gi, om,
                                                   nullptr, out);
    }
}

// Round 12
// 59.678 us; speedup vs baseline: 1.3764x; 1.0059x over previous
//
#include <hip/hip_runtime.h>
#include <hip/hip_bf16.h>
#include <math.h>

#define D_DIM   1024
#define NM      16
#define B_DIM   8
#define L_DIM   4096
#define SCALE_F 0.25f      // sqrt(1/N)
#define NK      5          // MFMA K-steps of 32 -> 160 taps total
#define WPB     4          // waves per block
#define TPW     4          // tiles per super-tile
#define NITER   4          // super-tiles (rows) per wave
#define LBUF    2560       // LDS bytes per buffer (20 x 128B)

typedef __attribute__((ext_vector_type(8))) short bf16x8;   // 8 bf16 (4 VGPRs)
typedef __attribute__((ext_vector_type(4))) float f32x4;

union U4 { uint4 u; bf16x8 v; };

__device__ __forceinline__ unsigned rot16(unsigned v) { return (v >> 16) | (v << 16); }
__device__ __forceinline__ unsigned short f2bf(float f) {
    __hip_bfloat16 h = __float2bfloat16(f);               // RNE
    return *reinterpret_cast<unsigned short*>(&h);
}
__device__ __forceinline__ float bflo(unsigned u) { return __uint_as_float(u << 16); }
__device__ __forceinline__ float bfhi(unsigned u) { return __uint_as_float(u & 0xffff0000u); }
// 16B-slot XOR swizzle (write and read identically); stays inside 128B blocks.
__device__ __forceinline__ int swz(int a) { return a ^ (((a >> 7) & 7) << 4); }

// ---------- A-fragment generation (unchanged from R8-R11) ----------
__global__ __launch_bounds__(256)
void ema_mkA(const float* __restrict__ p_logit, const float* __restrict__ lqr,
             const float* __restrict__ lqi, const float* __restrict__ gr,
             const float* __restrict__ gi, uint4* __restrict__ wsa)
{
    const int wid  = blockIdx.x * WPB + (threadIdx.x >> 6);   // 0 .. D*NK-1
    const int lane = threadIdx.x & 63;
    const int d    = wid / NK;
    const int k    = wid - d * NK;
    const int i    = lane & 15, g = lane >> 4;
    const int t0   = i - 15 + 32 * k + 8 * g;
    const float t0f = (float)t0;

    float acc[8];
#pragma unroll
    for (int e = 0; e < 8; ++e) acc[e] = 0.0f;

#pragma unroll 1
    for (int n = 0; n < NM; ++n) {
        const int idx = d * NM + n;
        const float pp = 1.0f / (1.0f + __expf(-p_logit[idx]));
        const float CR = gr[idx] * (SCALE_F * pp);
        const float CI = gi[idx] * (SCALE_F * pp);
        const float LR = lqr[idx], LI = lqi[idx];

        float sq, cq; __sincosf(LI, &sq, &cq);
        const float eq = __expf(LR);
        const float qr = eq * cq, qi = eq * sq;          // q
        float s0, c0; __sincosf(t0f * LI, &s0, &c0);
        const float e0 = __expf(t0f * LR);
        float wr = e0 * c0, wi = e0 * s0;                // q^t0

#pragma unroll
        for (int e = 0; e < 8; ++e) {
            acc[e] = fmaf(CR, wr, fmaf(-CI, wi, acc[e]));
            const float nwr = fmaf(wr, qr, -wi * qi);
            const float nwi = fmaf(wr, qi,  wi * qr);
            wr = nwr; wi = nwi;
        }
    }

    unsigned pk[4];
#pragma unroll
    for (int e = 0; e < 8; ++e) {
        const unsigned b = (t0 + e >= 0) ? (unsigned)f2bf(acc[e]) : 0u;
        if ((e & 1) == 0) pk[e >> 1] = b; else pk[e >> 1] |= b << 16;
    }
    wsa[(size_t)(d * NK + k) * 64 + lane] = make_uint4(pk[0], pk[1], pk[2], pk[3]);
}

// Fallback per-tap A-fragment (only if ws too small).
__device__ void compute_afrag(int d, int lane,
                              const float* __restrict__ p_logit,
                              const float* __restrict__ lqr,
                              const float* __restrict__ lqi,
                              const float* __restrict__ gr,
                              const float* __restrict__ gi,
                              bf16x8 (&af)[NK])
{
    float LR[NM], LI[NM], CR[NM], CI[NM];
#pragma unroll
    for (int n = 0; n < NM; ++n) {
        const int idx = d * NM + n;
        const float p = 1.0f / (1.0f + __expf(-p_logit[idx]));
        LR[n] = lqr[idx]; LI[n] = lqi[idx];
        CR[n] = gr[idx] * (SCALE_F * p);
        CI[n] = gi[idx] * (SCALE_F * p);
    }
    const int i = lane & 15, g = lane >> 4;
#pragma unroll
    for (int k = 0; k < NK; ++k) {
        unsigned pk[4] = {0, 0, 0, 0};
#pragma unroll
        for (int e = 0; e < 8; ++e) {
            const int t = i - 15 + 32 * k + 8 * g + e;
            float v = 0.0f;
            if (t >= 0) {
                const float tf = (float)t;
#pragma unroll
                for (int n = 0; n < NM; ++n) {
                    const float er = __expf(tf * LR[n]);
                    float s, c; __sincosf(tf * LI[n], &s, &c);
                    v += er * fmaf(CR[n], c, -CI[n] * s);
                }
            }
            const unsigned b = f2bf(v);
            if ((e & 1) == 0) pk[e >> 1] = b; else pk[e >> 1] |= b << 16;
        }
        U4 u; u.u = make_uint4(pk[0], pk[1], pk[2], pk[3]); af[k] = u.v;
    }
}

// Main kernel v7: PERSISTENT-STYLE waves. 8192 waves total; each wave owns
// one (d, qtr, bgrp) slot and iterates over 4 batch rows b = bgrp*4+i --
// 4x longer wave lifetime (R10/R11: short straight-line waves kept measured
// occupancy at 45% from dispatch churn), af loaded ONCE per wave (A-traffic
// /4), double-buffered LDS so iteration i's pack overlaps i-1's tail, and
// next-iter global loads are issued right after the pack frees the regs
// (~1500cy of MFMA covers L3/HBM latency). Per-tile math, swizzle, fragment
// layout byte-identical to R11.
template<bool FROM_WS>
__global__ __launch_bounds__(256)
void ema_fir(const float* __restrict__ x,
             const float* __restrict__ p_logit,
             const float* __restrict__ lqr, const float* __restrict__ lqi,
             const float* __restrict__ gr, const float* __restrict__ gi,
             const float* __restrict__ omega,
             const uint4* __restrict__ wsa,
             float* __restrict__ out)
{
    __shared__ __align__(16) char smem[WPB][2][LBUF];   // 20 KB/block

    const int w    = threadIdx.x >> 6;
    const int lane = threadIdx.x & 63;
    const int wid  = blockIdx.x * WPB + w;      // 0 .. 8191
    const int d    = wid >> 3;
    const int sub  = wid & 7;
    const int qtr  = sub & 3;                   // quarter-row (fixed per wave)
    const int bgrp = sub >> 2;                  // batch group: rows bgrp*4 .. +3
    const int j    = lane & 15, g = lane >> 4;

    const size_t rstride = (size_t)D_DIM * L_DIM;           // floats per batch
    const float* xcol = x   + (size_t)(bgrp * 4 * D_DIM + d) * L_DIM + qtr * 1024;
    float*       ycol = out + (size_t)(bgrp * 4 * D_DIM + d) * L_DIM + qtr * 1024;

    const float om = omega[d];

    bf16x8 af[NK];
    if (FROM_WS) {
#pragma unroll
        for (int k = 0; k < NK; ++k) {
            U4 u; u.u = wsa[(size_t)(d * NK + k) * 64 + lane];
            af[k] = u.v;
        }
    } else {
        compute_afrag(d, lane, p_logit, lqr, lqi, gr, gi, af);
    }

    // ---- prologue: issue iteration 0's loads ----
    float4 c4 = make_float4(0.f, 0.f, 0.f, 0.f);
    if (qtr != 0)
        c4 = *reinterpret_cast<const float4*>(xcol - 256 + lane * 4);
    float4 r[4];
#pragma unroll
    for (int v = 0; v < 4; ++v)
        r[v] = *reinterpret_cast<const float4*>(xcol + lane * 16 + 4 * v);

#pragma unroll 1
    for (int i = 0; i < NITER; ++i) {
        char* sb = smem[w][i & 1];

        // ---- pack current row's window into LDS (vmcnt wait lands here) ----
        {
            uint2 cpk;
            cpk.x = (unsigned)f2bf(c4.x) | ((unsigned)f2bf(c4.y) << 16);
            cpk.y = (unsigned)f2bf(c4.z) | ((unsigned)f2bf(c4.w) << 16);
            *reinterpret_cast<uint2*>(sb + swz(lane * 8)) = cpk;

            unsigned pk[8];
#pragma unroll
            for (int v = 0; v < 4; ++v) {
                pk[2 * v + 0] = (unsigned)f2bf(r[v].x) | ((unsigned)f2bf(r[v].y) << 16);
                pk[2 * v + 1] = (unsigned)f2bf(r[v].z) | ((unsigned)f2bf(r[v].w) << 16);
            }
            const int wbase = 512 + lane * 32;
            *reinterpret_cast<uint4*>(sb + swz(wbase))      = make_uint4(pk[0], pk[1], pk[2], pk[3]);
            *reinterpret_cast<uint4*>(sb + swz(wbase + 16)) = make_uint4(pk[4], pk[5], pk[6], pk[7]);
        }

        // ---- issue next row's loads now (regs free; covered by compute) ----
        if (i < NITER - 1) {
            const float* xn = xcol + (size_t)(i + 1) * rstride;
            if (qtr != 0)
                c4 = *reinterpret_cast<const float4*>(xn - 256 + lane * 4);
#pragma unroll
            for (int v = 0; v < 4; ++v)
                r[v] = *reinterpret_cast<const float4*>(xn + lane * 16 + 4 * v);
        }

        // ---- compute 4 tiles from LDS (4 independent MFMA chains) ----
        float* yb = ycol + (size_t)i * rstride;
#pragma unroll
        for (int tt = 0; tt < TPW; ++tt) {
            f32x4 acc = {0.0f, 0.0f, 0.0f, 0.0f};
#pragma unroll
            for (int k = 0; k < NK; ++k) {
                const int boff = 512 * tt + 528 + 32 * j - 64 * k - 16 * g;  // [224,2544]
                U4 z; z.u = *reinterpret_cast<const uint4*>(sb + swz(boff));
                uint4 rv;
                rv.x = rot16(z.u.w); rv.y = rot16(z.u.z);
                rv.z = rot16(z.u.y); rv.w = rot16(z.u.x);
                U4 bfv; bfv.u = rv;
                acc = __builtin_amdgcn_mfma_f32_16x16x32_bf16(af[k], bfv.v, acc, 0, 0, 0);
            }
            const int lx = 512 * tt + 512 + 32 * j + 8 * g;    // <= 2552
            const uint2 z2 = *reinterpret_cast<const uint2*>(sb + swz(lx));
            acc.x = fmaf(om, bflo(z2.x), acc.x);
            acc.y = fmaf(om, bfhi(z2.x), acc.y);
            acc.z = fmaf(om, bflo(z2.y), acc.z);
            acc.w = fmaf(om, bfhi(z2.y), acc.w);
            __builtin_nontemporal_store(acc,
                reinterpret_cast<f32x4*>(yb + tt * 256 + 16 * j + 4 * g));
        }
    }
}

extern "C" void kernel_launch(void* const* d_in, const int* in_sizes, int n_in,
                              void* d_out, int out_size, void* d_ws, size_t ws_size,
                              hipStream_t stream)
{
    const float* x   = (const float*)d_in[0];
    const float* pl  = (const float*)d_in[1];
    const float* lqr = (const float*)d_in[2];
    const float* lqi = (const float*)d_in[3];
    const float* gr  = (const float*)d_in[4];
    const float* gi  = (const float*)d_in[5];
    const float* om  = (const float*)d_in[6];
    float* out = (float*)d_out;

    const size_t needA = (size_t)D_DIM * NK * 64 * 16;   // 5.24 MB of A-fragments
    dim3 grid((D_DIM * 8) / WPB), block(64 * WPB);       // 8192 waves, 4 rows each

    if (ws_size >= needA) {
        ema_mkA<<<dim3(D_DIM * NK / WPB), dim3(64 * WPB), 0, stream>>>(
            pl, lqr, lqi, gr, gi, (uint4*)d_ws);
        ema_fir<true><<<grid, block, 0, stream>>>(x, pl, lqr, lqi, gr, gi, om,
                                                  (const uint4*)d_ws, out);
    } else {
        ema_fir<false><<<grid, block, 0, stream>>>(x, pl, lqr, lqi, gr, gi, om,
                                                   nullptr, out);
    }
}

// Round 13
// 52.854 us; speedup vs baseline: 1.5540x; 1.1291x over previous
//
#include <hip/hip_runtime.h>
#include <hip/hip_bf16.h>
#include <math.h>

#define D_DIM   1024
#define NM      16
#define B_DIM   8
#define L_DIM   4096
#define SCALE_F 0.25f      // sqrt(1/N)
#define NK      5          // MFMA K-steps of 32 -> 160 taps total
#define NITER   4          // batch rows per block
#define SROW    9216       // staged row bytes: 512B zero-pad + 4096 bf16

typedef __attribute__((ext_vector_type(8))) short bf16x8;   // 8 bf16 (4 VGPRs)
typedef __attribute__((ext_vector_type(4))) float f32x4;

union U4 { uint4 u; bf16x8 v; };

__device__ __forceinline__ unsigned rot16(unsigned v) { return (v >> 16) | (v << 16); }
__device__ __forceinline__ unsigned short f2bf(float f) {
    __hip_bfloat16 h = __float2bfloat16(f);               // RNE
    return *reinterpret_cast<unsigned short*>(&h);
}
__device__ __forceinline__ float bflo(unsigned u) { return __uint_as_float(u << 16); }
__device__ __forceinline__ float bfhi(unsigned u) { return __uint_as_float(u & 0xffff0000u); }
// 16B-slot XOR swizzle (write and read identically); bijective within 1KB.
__device__ __forceinline__ int swz(int a) { return a ^ (((a >> 7) & 7) << 4); }

// A-fragment for K-step k of dimension d (same tap layout as R8-R12 mkA):
// A[i,t'] = kernel_d[i + t'], lane=(i | g<<4), t' = 32k + 8g + e - 15.
// Per mode: q, q^t0 via exp/sincos once, then 7 complex mults walk the taps.
__device__ void compute_af_k(int d, int lane, int k,
                             const float* __restrict__ p_logit,
                             const float* __restrict__ lqr,
                             const float* __restrict__ lqi,
                             const float* __restrict__ gr,
                             const float* __restrict__ gi,
                             char* __restrict__ afb)
{
    const int i = lane & 15, g = lane >> 4;
    const int t0 = i - 15 + 32 * k + 8 * g;
    const float t0f = (float)t0;

    float acc[8];
#pragma unroll
    for (int e = 0; e < 8; ++e) acc[e] = 0.0f;

#pragma unroll 1
    for (int n = 0; n < NM; ++n) {
        const int idx = d * NM + n;
        const float pp = 1.0f / (1.0f + __expf(-p_logit[idx]));
        const float CR = gr[idx] * (SCALE_F * pp);
        const float CI = gi[idx] * (SCALE_F * pp);
        const float LR = lqr[idx], LI = lqi[idx];

        float sq, cq; __sincosf(LI, &sq, &cq);
        const float eq = __expf(LR);
        const float qr = eq * cq, qi = eq * sq;          // q
        float s0, c0; __sincosf(t0f * LI, &s0, &c0);
        const float e0 = __expf(t0f * LR);
        float wr = e0 * c0, wi = e0 * s0;                // q^t0

#pragma unroll
        for (int e = 0; e < 8; ++e) {
            acc[e] = fmaf(CR, wr, fmaf(-CI, wi, acc[e]));
            const float nwr = fmaf(wr, qr, -wi * qi);
            const float nwi = fmaf(wr, qi,  wi * qr);
            wr = nwr; wi = nwi;
        }
    }

    unsigned pk[4];
#pragma unroll
    for (int e = 0; e < 8; ++e) {
        const unsigned b = (t0 + e >= 0) ? (unsigned)f2bf(acc[e]) : 0u;
        if ((e & 1) == 0) pk[e >> 1] = b; else pk[e >> 1] |= b << 16;
    }
    *reinterpret_cast<uint4*>(afb + k * 1024 + lane * 16) =
        make_uint4(pk[0], pk[1], pk[2], pk[3]);
}

// Fused kernel v8: block = (d, bgrp); its 4 waves are the 4 QUARTERS of the
// same row, iterating over 4 batch rows b = bgrp*4+i. The whole 4096-row is
// staged cooperatively per iteration (16KB contiguous block read, 9216B bf16
// dbuf) -- context loads vanish (each wave's left context is the neighbor
// quarter). The af table is computed ONCE per block (wave w -> k=w, wave 0
// also k=4) and shared via 5KB LDS: kills the separate mkA kernel, its
// launch bubble, and ~45MB of af+context request traffic (R12 post-mortem).
// Tile offsets = 2048*qtr + R12 offsets (max 8704 <= 9216); swizzle,
// reversal, MFMA fragment layout byte-identical to R10-R12 (absmax 0.0625).
__global__ __launch_bounds__(256)
void ema_fused(const float* __restrict__ x,
               const float* __restrict__ p_logit,
               const float* __restrict__ lqr, const float* __restrict__ lqi,
               const float* __restrict__ gr, const float* __restrict__ gi,
               const float* __restrict__ omega,
               float* __restrict__ out)
{
    __shared__ __align__(16) char sstage[2][SROW];   // 18 KB
    __shared__ __align__(16) char safb[NK * 1024];   // 5 KB

    const int tid  = threadIdx.x;
    const int w    = tid >> 6;                  // wave = quarter
    const int lane = tid & 63;
    const int bid  = blockIdx.x;
    const int d    = bid >> 1;
    const int bgrp = bid & 1;                   // rows bgrp*4 .. bgrp*4+3
    const int j    = lane & 15, g = lane >> 4;

    const size_t rstride = (size_t)D_DIM * L_DIM;
    const float* xrow0 = x   + (size_t)(bgrp * 4 * D_DIM + d) * L_DIM;
    float*       yrow0 = out + (size_t)(bgrp * 4 * D_DIM + d) * L_DIM;
    const float  om    = omega[d];

    // ---- zero pads of both buffers: bytes [0,512) (swz maps region to itself) ----
    if (tid < 64) {
        const int h = tid & 31, buf = tid >> 5;
        *reinterpret_cast<uint4*>(sstage[buf] + swz(h * 16)) =
            make_uint4(0u, 0u, 0u, 0u);
    }

    // ---- issue row 0 loads (16 consecutive floats per thread, 16KB/block) ----
    float4 r[4];
#pragma unroll
    for (int v = 0; v < 4; ++v)
        r[v] = *reinterpret_cast<const float4*>(xrow0 + tid * 16 + 4 * v);

    // ---- cooperative af: wave w computes K-step w; wave 0 also k=4 ----
    compute_af_k(d, lane, w, p_logit, lqr, lqi, gr, gi, safb);
    if (w == 0)
        compute_af_k(d, lane, 4, p_logit, lqr, lqi, gr, gi, safb);

    __syncthreads();                            // af + pads visible

    bf16x8 af[NK];
#pragma unroll
    for (int k = 0; k < NK; ++k) {
        U4 u; u.u = *reinterpret_cast<const uint4*>(safb + k * 1024 + lane * 16);
        af[k] = u.v;
    }

    // ---- pack row 0 -> buf0, issue row 1 loads ----
    {
        unsigned pk[8];
#pragma unroll
        for (int v = 0; v < 4; ++v) {
            pk[2 * v + 0] = (unsigned)f2bf(r[v].x) | ((unsigned)f2bf(r[v].y) << 16);
            pk[2 * v + 1] = (unsigned)f2bf(r[v].z) | ((unsigned)f2bf(r[v].w) << 16);
        }
        const int wb = 512 + tid * 32;
        *reinterpret_cast<uint4*>(sstage[0] + swz(wb))      = make_uint4(pk[0], pk[1], pk[2], pk[3]);
        *reinterpret_cast<uint4*>(sstage[0] + swz(wb + 16)) = make_uint4(pk[4], pk[5], pk[6], pk[7]);
    }
#pragma unroll
    for (int v = 0; v < 4; ++v)
        r[v] = *reinterpret_cast<const float4*>(xrow0 + rstride + tid * 16 + 4 * v);

    __syncthreads();                            // buf0 ready

#pragma unroll 1
    for (int i = 0; i < NITER; ++i) {
        const char* sb = sstage[i & 1];
        float* yb = yrow0 + (size_t)i * rstride + w * 1024;

        // ---- compute this wave's quarter: 4 tiles from shared row buffer ----
#pragma unroll
        for (int tt = 0; tt < 4; ++tt) {
            f32x4 acc = {0.0f, 0.0f, 0.0f, 0.0f};
#pragma unroll
            for (int k = 0; k < NK; ++k) {
                const int boff = 2048 * w + 512 * tt + 528 + 32 * j - 64 * k - 16 * g;
                U4 z; z.u = *reinterpret_cast<const uint4*>(sb + swz(boff));
                uint4 rv;
                rv.x = rot16(z.u.w); rv.y = rot16(z.u.z);
                rv.z = rot16(z.u.y); rv.w = rot16(z.u.x);
                U4 bfv; bfv.u = rv;
                acc = __builtin_amdgcn_mfma_f32_16x16x32_bf16(af[k], bfv.v, acc, 0, 0, 0);
            }
            const int lx = 2048 * w + 512 * tt + 512 + 32 * j + 8 * g;
            const uint2 z2 = *reinterpret_cast<const uint2*>(sb + swz(lx));
            acc.x = fmaf(om, bflo(z2.x), acc.x);
            acc.y = fmaf(om, bfhi(z2.x), acc.y);
            acc.z = fmaf(om, bflo(z2.y), acc.z);
            acc.w = fmaf(om, bfhi(z2.y), acc.w);
            __builtin_nontemporal_store(acc,
                reinterpret_cast<f32x4*>(yb + tt * 256 + 16 * j + 4 * g));
        }

        // ---- stage row i+1 into the other buffer; issue row i+2 loads ----
        if (i < NITER - 1) {
            char* nb = sstage[(i + 1) & 1];
            unsigned pk[8];
#pragma unroll
            for (int v = 0; v < 4; ++v) {
                pk[2 * v + 0] = (unsigned)f2bf(r[v].x) | ((unsigned)f2bf(r[v].y) << 16);
                pk[2 * v + 1] = (unsigned)f2bf(r[v].z) | ((unsigned)f2bf(r[v].w) << 16);
            }
            const int wb = 512 + tid * 32;
            *reinterpret_cast<uint4*>(nb + swz(wb))      = make_uint4(pk[0], pk[1], pk[2], pk[3]);
            *reinterpret_cast<uint4*>(nb + swz(wb + 16)) = make_uint4(pk[4], pk[5], pk[6], pk[7]);

            if (i < NITER - 2) {
#pragma unroll
                for (int v = 0; v < 4; ++v)
                    r[v] = *reinterpret_cast<const float4*>(
                        xrow0 + (size_t)(i + 2) * rstride + tid * 16 + 4 * v);
            }
            __syncthreads();                    // next buf ready; cur buf free
        }
    }
}

extern "C" void kernel_launch(void* const* d_in, const int* in_sizes, int n_in,
                              void* d_out, int out_size, void* d_ws, size_t ws_size,
                              hipStream_t stream)
{
    const float* x   = (const float*)d_in[0];
    const float* pl  = (const float*)d_in[1];
    const float* lqr = (const float*)d_in[2];
    const float* lqi = (const float*)d_in[3];
    const float* gr  = (const float*)d_in[4];
    const float* gi  = (const float*)d_in[5];
    const float* om  = (const float*)d_in[6];
    float* out = (float*)d_out;

    dim3 grid(D_DIM * 2), block(256);    // block = (d, bgrp); 4 waves = 4 quarters
    ema_fused<<<grid, block, 0, stream>>>(x, pl, lqr, lqi, gr, gi, om, out);
}

// Round 14
// 50.188 us; speedup vs baseline: 1.6366x; 1.0531x over previous
//
#include <hip/hip_runtime.h>
#include <hip/hip_bf16.h>
#include <math.h>

#define D_DIM   1024
#define NM      16
#define B_DIM   8
#define L_DIM   4096
#define SCALE_F 0.25f      // sqrt(1/N)
#define NK      5          // MFMA K-steps of 32 -> 160 taps total
#define NITER   8          // all 8 batch rows per block (persistent, grid=1024)
#define SROW    8704       // staged row bytes: 4096 bf16 reversed + 512B zero-pad

typedef __attribute__((ext_vector_type(8))) short bf16x8;   // 8 bf16 (4 VGPRs)
typedef __attribute__((ext_vector_type(4))) float f32x4;

union U4 { uint4 u; bf16x8 v; };

__device__ __forceinline__ unsigned short f2bf(float f) {
    __hip_bfloat16 h = __float2bfloat16(f);               // RNE
    return *reinterpret_cast<unsigned short*>(&h);
}
__device__ __forceinline__ float bflo(unsigned u) { return __uint_as_float(u << 16); }
__device__ __forceinline__ float bfhi(unsigned u) { return __uint_as_float(u & 0xffff0000u); }
// 16B-slot XOR swizzle (write and read identically); keeps bits 0-3, stays
// within each 1KB region; all accesses are >=8B aligned -> never split.
__device__ __forceinline__ int swz(int a) { return a ^ (((a >> 7) & 7) << 4); }

// A-fragment for K-step k of dimension d (tap layout unchanged since R8):
// A[i,t'] = kernel_d[i + t'], lane=(i | g<<4), t' = 32k + 8g + e - 15.
__device__ void compute_af_k(int d, int lane, int k,
                             const float* __restrict__ p_logit,
                             const float* __restrict__ lqr,
                             const float* __restrict__ lqi,
                             const float* __restrict__ gr,
                             const float* __restrict__ gi,
                             char* __restrict__ afb)
{
    const int i = lane & 15, g = lane >> 4;
    const int t0 = i - 15 + 32 * k + 8 * g;
    const float t0f = (float)t0;

    float acc[8];
#pragma unroll
    for (int e = 0; e < 8; ++e) acc[e] = 0.0f;

#pragma unroll 1
    for (int n = 0; n < NM; ++n) {
        const int idx = d * NM + n;
        const float pp = 1.0f / (1.0f + __expf(-p_logit[idx]));
        const float CR = gr[idx] * (SCALE_F * pp);
        const float CI = gi[idx] * (SCALE_F * pp);
        const float LR = lqr[idx], LI = lqi[idx];

        float sq, cq; __sincosf(LI, &sq, &cq);
        const float eq = __expf(LR);
        const float qr = eq * cq, qi = eq * sq;          // q
        float s0, c0; __sincosf(t0f * LI, &s0, &c0);
        const float e0 = __expf(t0f * LR);
        float wr = e0 * c0, wi = e0 * s0;                // q^t0

#pragma unroll
        for (int e = 0; e < 8; ++e) {
            acc[e] = fmaf(CR, wr, fmaf(-CI, wi, acc[e]));
            const float nwr = fmaf(wr, qr, -wi * qi);
            const float nwi = fmaf(wr, qi,  wi * qr);
            wr = nwr; wi = nwi;
        }
    }

    unsigned pk[4];
#pragma unroll
    for (int e = 0; e < 8; ++e) {
        const unsigned b = (t0 + e >= 0) ? (unsigned)f2bf(acc[e]) : 0u;
        if ((e & 1) == 0) pk[e >> 1] = b; else pk[e >> 1] |= b << 16;
    }
    *reinterpret_cast<uint4*>(afb + k * 1024 + lane * 16) =
        make_uint4(pk[0], pk[1], pk[2], pk[3]);
}

// v9: persistent fused kernel. Block = d (grid 1024 = exactly 4 blocks/CU,
// fully resident, zero dispatch churn); 4 waves = 4 quarters of the row;
// 8 batch rows per block, double-buffered cooperative staging.
// KEY CHANGE vs R13: the row is stored TIME-REVERSED in LDS (x[l] at byte
// 2*(4095-l); zero-pad for l<0 at bytes [8192,8704)). The pack permutes
// halfwords for free, and every B-fragment becomes a DIRECT ds_read_b128 --
// the 80 rot16+mov per wave-row (4x the MFMA count; R13 VALUBusy 37%) vanish.
// Element mapping e <-> x[L-e] (L = 1024w+256tt+15+16j-32k-8g) identical to
// the R10-R13 verified kernels => absmax 0.0625 preserved.
__global__ __launch_bounds__(256)
void ema_fused(const float* __restrict__ x,
               const float* __restrict__ p_logit,
               const float* __restrict__ lqr, const float* __restrict__ lqi,
               const float* __restrict__ gr, const float* __restrict__ gi,
               const float* __restrict__ omega,
               float* __restrict__ out)
{
    __shared__ __align__(16) char sstage[2][SROW];   // 17 KB
    __shared__ __align__(16) char safb[NK * 1024];   // 5 KB

    const int tid  = threadIdx.x;
    const int w    = tid >> 6;                  // wave = quarter of the row
    const int lane = tid & 63;
    const int d    = blockIdx.x;
    const int j    = lane & 15, g = lane >> 4;

    const size_t rstride = (size_t)D_DIM * L_DIM;
    const float* xrow0 = x   + (size_t)d * L_DIM;
    float*       yrow0 = out + (size_t)d * L_DIM;
    const float  om    = omega[d];

    // ---- zero pads of both buffers: bytes [8192,8704) = x[-256..-1] ----
    if (tid < 64) {
        const int buf = tid >> 5, h = tid & 31;
        *reinterpret_cast<uint4*>(sstage[buf] + swz(8192 + h * 16)) =
            make_uint4(0u, 0u, 0u, 0u);
    }

    // ---- issue row 0 loads (16 consecutive floats per thread) ----
    float4 r[4];
#pragma unroll
    for (int v = 0; v < 4; ++v)
        r[v] = *reinterpret_cast<const float4*>(xrow0 + tid * 16 + 4 * v);

    // ---- cooperative af: wave w computes K-step w; wave 0 also k=4 ----
    compute_af_k(d, lane, w, p_logit, lqr, lqi, gr, gi, safb);
    if (w == 0)
        compute_af_k(d, lane, 4, p_logit, lqr, lqi, gr, gi, safb);

    __syncthreads();                            // af + pads visible

    bf16x8 af[NK];
#pragma unroll
    for (int k = 0; k < NK; ++k) {
        U4 u; u.u = *reinterpret_cast<const uint4*>(safb + k * 1024 + lane * 16);
        af[k] = u.v;
    }

    // Reversed pack: thread covers x[16tid..16tid+15] -> bytes 8160-32tid,
    // halfword hw = 15 - e_local (hw pairs: word W = {e=15-2W lo, e=14-2W hi}).
#define PACK(dst)                                                              \
    {                                                                          \
        unsigned pk[8];                                                        \
        pk[0] = (unsigned)f2bf(r[3].w) | ((unsigned)f2bf(r[3].z) << 16);       \
        pk[1] = (unsigned)f2bf(r[3].y) | ((unsigned)f2bf(r[3].x) << 16);       \
        pk[2] = (unsigned)f2bf(r[2].w) | ((unsigned)f2bf(r[2].z) << 16);       \
        pk[3] = (unsigned)f2bf(r[2].y) | ((unsigned)f2bf(r[2].x) << 16);       \
        pk[4] = (unsigned)f2bf(r[1].w) | ((unsigned)f2bf(r[1].z) << 16);       \
        pk[5] = (unsigned)f2bf(r[1].y) | ((unsigned)f2bf(r[1].x) << 16);       \
        pk[6] = (unsigned)f2bf(r[0].w) | ((unsigned)f2bf(r[0].z) << 16);       \
        pk[7] = (unsigned)f2bf(r[0].y) | ((unsigned)f2bf(r[0].x) << 16);       \
        const int base = 8160 - tid * 32;                                      \
        *reinterpret_cast<uint4*>((dst) + swz(base)) =                         \
            make_uint4(pk[0], pk[1], pk[2], pk[3]);                            \
        *reinterpret_cast<uint4*>((dst) + swz(base + 16)) =                    \
            make_uint4(pk[4], pk[5], pk[6], pk[7]);                            \
    }

    // ---- pack row 0 -> buf0, issue row 1 loads ----
    PACK(sstage[0]);
#pragma unroll
    for (int v = 0; v < 4; ++v)
        r[v] = *reinterpret_cast<const float4*>(xrow0 + rstride + tid * 16 + 4 * v);

    __syncthreads();                            // buf0 ready

#pragma unroll 1
    for (int i = 0; i < NITER; ++i) {
        const char* sb = sstage[i & 1];
        float* yb = yrow0 + (size_t)i * rstride + w * 1024;

        // ---- this wave's quarter: 4 tiles, direct ds_read_b128 (no reversal) ----
#pragma unroll
        for (int tt = 0; tt < 4; ++tt) {
            f32x4 acc = {0.0f, 0.0f, 0.0f, 0.0f};
#pragma unroll
            for (int k = 0; k < NK; ++k) {
                const int rboff = 8160 - 2048 * w - 512 * tt - 32 * j + 64 * k + 16 * g;
                U4 z; z.u = *reinterpret_cast<const uint4*>(sb + swz(rboff));
                acc = __builtin_amdgcn_mfma_f32_16x16x32_bf16(af[k], z.v, acc, 0, 0, 0);
            }
            const int roff = 8184 - 2048 * w - 512 * tt - 32 * j - 8 * g;
            const uint2 z2 = *reinterpret_cast<const uint2*>(sb + swz(roff));
            acc.x = fmaf(om, bfhi(z2.y), acc.x);    // x[lpos]
            acc.y = fmaf(om, bflo(z2.y), acc.y);    // x[lpos+1]
            acc.z = fmaf(om, bfhi(z2.x), acc.z);    // x[lpos+2]
            acc.w = fmaf(om, bflo(z2.x), acc.w);    // x[lpos+3]
            __builtin_nontemporal_store(acc,
                reinterpret_cast<f32x4*>(yb + tt * 256 + 16 * j + 4 * g));
        }

        // ---- stage row i+1 into the other buffer; issue row i+2 loads ----
        if (i < NITER - 1) {
            char* nb = sstage[(i + 1) & 1];
            PACK(nb);
            if (i < NITER - 2) {
#pragma unroll
                for (int v = 0; v < 4; ++v)
                    r[v] = *reinterpret_cast<const float4*>(
                        xrow0 + (size_t)(i + 2) * rstride + tid * 16 + 4 * v);
            }
            __syncthreads();                    // next buf ready; cur buf free
        }
    }
#undef PACK
}

extern "C" void kernel_launch(void* const* d_in, const int* in_sizes, int n_in,
                              void* d_out, int out_size, void* d_ws, size_t ws_size,
                              hipStream_t stream)
{
    const float* x   = (const float*)d_in[0];
    const float* pl  = (const float*)d_in[1];
    const float* lqr = (const float*)d_in[2];
    const float* lqi = (const float*)d_in[3];
    const float* gr  = (const float*)d_in[4];
    const float* gi  = (const float*)d_in[5];
    const float* om  = (const float*)d_in[6];
    float* out = (float*)d_out;

    dim3 grid(D_DIM), block(256);   // persistent: 1024 blocks = 4/CU resident
    ema_fused<<<grid, block, 0, stream>>>(x, pl, lqr, lqi, gr, gi, om, out);
}